// Round 1
// baseline (312.883 us; speedup 1.0000x reference)
//
#include <hip/hip_runtime.h>

// QuantizedEmbedding: out[token, :] = float(weight_q[x[token], :]) * scales[x[token]]
// tokens = BATCH*SEQ = 16384, DIM = 512, VOCAB = 128000.
// Memory-bound gather: each token row is 2 KiB contiguous (512 x int32),
// read vectorized as int4 (16 B/lane), written as float4.

#define DIM 512
#define DIMV (DIM / 4)   // 128 int4 per row

__global__ void __launch_bounds__(256) qemb_kernel(
    const int* __restrict__ x,        // [n_tokens] int32 indices
    const int* __restrict__ wq,       // [VOCAB, DIM] int32 (int8-valued)
    const float* __restrict__ scales, // [VOCAB] fp32
    float* __restrict__ out,          // [n_tokens, DIM] fp32
    long long total_vec)              // n_tokens * DIMV
{
    long long gid = (long long)blockIdx.x * blockDim.x + threadIdx.x;
    if (gid >= total_vec) return;

    int token = (int)(gid >> 7);   // gid / DIMV
    int dv    = (int)(gid & (DIMV - 1));

    int row = x[token];            // same value across 128 consecutive threads -> broadcast
    float s = scales[row];

    const int4* wrow = reinterpret_cast<const int4*>(wq + (long long)row * DIM);
    int4 w = wrow[dv];

    float4 o;
    o.x = (float)w.x * s;
    o.y = (float)w.y * s;
    o.z = (float)w.z * s;
    o.w = (float)w.w * s;

    reinterpret_cast<float4*>(out)[gid] = o;
}

extern "C" void kernel_launch(void* const* d_in, const int* in_sizes, int n_in,
                              void* d_out, int out_size, void* d_ws, size_t ws_size,
                              hipStream_t stream) {
    const int*   x      = (const int*)d_in[0];    // [B*S] int32
    const int*   wq     = (const int*)d_in[1];    // [VOCAB*DIM] int32
    const float* scales = (const float*)d_in[2];  // [VOCAB] fp32
    float* out = (float*)d_out;

    int n_tokens = in_sizes[0];                      // 16384
    long long total_vec = (long long)n_tokens * DIMV; // 2,097,152

    const int block = 256;
    int grid = (int)((total_vec + block - 1) / block);
    qemb_kernel<<<grid, block, 0, stream>>>(x, wq, scales, out, total_vec);
}

// Round 4
// 310.725 us; speedup vs baseline: 1.0069x; 1.0069x over previous
//
#include <hip/hip_runtime.h>

// QuantizedEmbedding: out[token, :] = float(weight_q[x[token], :]) * scales[x[token]]
// tokens = BATCH*SEQ = 16384, DIM = 512, VOCAB = 128000.
// Memory-bound gather: each token row is 2 KiB contiguous (512 x int32),
// read as 16B/lane, written as nontemporal 16B float stores.
// Round-2 notes: reported dur_us is dominated by harness reset traffic
// (1 GB d_ws poison = 160 us + 262 MB input restore ~80 us); kernel itself
// is ~10-20 us (absent from rocprof top-5, all fills at 159 us).
// Round-3 fix: __builtin_nontemporal_store needs clang ext_vector types,
// not HIP_vector_type float4.
// Round-4: resubmit unchanged (round 3 was a GPU-acquisition timeout).

#define DIM 512
#define DIMV (DIM / 4)   // 128 16B-vectors per row

typedef float f32x4 __attribute__((ext_vector_type(4)));
typedef int   i32x4 __attribute__((ext_vector_type(4)));

__global__ void __launch_bounds__(256) qemb_kernel(
    const int* __restrict__ x,        // [n_tokens] int32 indices
    const int* __restrict__ wq,       // [VOCAB, DIM] int32 (int8-valued)
    const float* __restrict__ scales, // [VOCAB] fp32
    float* __restrict__ out,          // [n_tokens, DIM] fp32
    long long total_vec)              // n_tokens * DIMV
{
    long long gid = (long long)blockIdx.x * blockDim.x + threadIdx.x;
    if (gid >= total_vec) return;

    int token = (int)(gid >> 7);   // gid / DIMV
    int dv    = (int)(gid & (DIMV - 1));

    // x[token] is identical across all 64 lanes of the wave (128 consecutive
    // threads share one token; a wave never straddles tokens) -> force scalar.
    int row = __builtin_amdgcn_readfirstlane(x[token]);
    float s = scales[row];         // uniform -> scalar load

    const i32x4* wrow = reinterpret_cast<const i32x4*>(wq + (long long)row * DIM);
    i32x4 w = wrow[dv];

    f32x4 o;
    o.x = (float)w.x * s;
    o.y = (float)w.y * s;
    o.z = (float)w.z * s;
    o.w = (float)w.w * s;

    // Output is write-once: nontemporal store keeps L2 free for the gather.
    __builtin_nontemporal_store(o, reinterpret_cast<f32x4*>(out) + gid);
}

extern "C" void kernel_launch(void* const* d_in, const int* in_sizes, int n_in,
                              void* d_out, int out_size, void* d_ws, size_t ws_size,
                              hipStream_t stream) {
    const int*   x      = (const int*)d_in[0];    // [B*S] int32
    const int*   wq     = (const int*)d_in[1];    // [VOCAB*DIM] int32
    const float* scales = (const float*)d_in[2];  // [VOCAB] fp32
    float* out = (float*)d_out;

    int n_tokens = in_sizes[0];                       // 16384
    long long total_vec = (long long)n_tokens * DIMV; // 2,097,152

    const int block = 256;
    int grid = (int)((total_vec + block - 1) / block);
    qemb_kernel<<<grid, block, 0, stream>>>(x, wq, scales, out, total_vec);
}